// Round 4
// baseline (545.991 us; speedup 1.0000x reference)
//
#include <hip/hip_runtime.h>
#include <math.h>

#define D 256
#define NWAVES 4
// One row per 16-lane group: 4 rows per wave iteration, waves stride 16 rows.
// Lane l: grp = l>>4 (row), c = l&15 (column block); covers cols 4c+64j, j=0..3.

__global__ __launch_bounds__(256, 4)
void gap_kernel(const float* __restrict__ feat,
                const float* __restrict__ W_gate,
                const float* __restrict__ b_gate,
                const int* __restrict__ seg,
                float* __restrict__ out, int N)
{
    const int b    = blockIdx.x;
    const int tid  = threadIdx.x;
    const int lane = tid & 63;
    const int wave = tid >> 6;
    const int grp  = lane >> 4;      // row within the wave's 4-row quad
    const int c    = lane & 15;      // column-block index

    // Binary search for segment bounds [lo, hi). seg[] sorted; same-address
    // broadcast loads, no divergence.
    int lo, hi;
    {
        int l = 0, r = N;
        while (l < r) { int m = (l + r) >> 1; if (seg[m] < b) l = m + 1; else r = m; }
        lo = l; r = N;
        while (l < r) { int m = (l + r) >> 1; if (seg[m] < b + 1) l = m + 1; else r = m; }
        hi = l;
    }

    __shared__ float  s_l[NWAVES];
    __shared__ float4 s_acc[NWAVES][64];     // 4 KB

    if (hi <= lo) {                          // empty segment (block-uniform)
        out[(size_t)b * D + tid] = 0.0f;
        return;
    }

    // Per-lane weight fragment (bias dropped: softmax-invariant, and b=0).
    const float4* __restrict__ Wv = (const float4*)W_gate;
    float4 w[4];
    #pragma unroll
    for (int j = 0; j < 4; ++j) w[j] = Wv[c + 16 * j];

    const float4* __restrict__ Fv = (const float4*)feat;  // row n at Fv[n*64]
    const int last = hi - 1;

    float  l_run = 0.0f;
    float4 acc[4];
    #pragma unroll
    for (int j = 0; j < 4; ++j) acc[j] = make_float4(0.f, 0.f, 0.f, 0.f);

    int base = lo + wave * 4;                // this wave's first row quad

    // Depth-2 prefetch pipeline: 8 KB/wave in flight during compute.
    float4 fa[4], fb[4];
    {
        const size_t ra = (size_t)min(base + grp, last) * 64;
        #pragma unroll
        for (int j = 0; j < 4; ++j) fa[j] = Fv[ra + c + 16 * j];
        const size_t rb = (size_t)min(base + 16 + grp, last) * 64;
        #pragma unroll
        for (int j = 0; j < 4; ++j) fb[j] = Fv[rb + c + 16 * j];
    }

    for (; base < hi; base += 16) {
        float4 ft[4];                        // prefetch quad at base+32
        {
            const size_t rt = (size_t)min(base + 32 + grp, last) * 64;
            #pragma unroll
            for (int j = 0; j < 4; ++j) ft[j] = Fv[rt + c + 16 * j];
        }

        // gate partial dot: 16 fma, then 4-stage reduce across the 16-lane group
        float p = 0.0f;
        #pragma unroll
        for (int j = 0; j < 4; ++j)
            p += fa[j].x * w[j].x + fa[j].y * w[j].y
               + fa[j].z * w[j].z + fa[j].w * w[j].w;
        #pragma unroll
        for (int off = 8; off >= 1; off >>= 1)
            p += __shfl_xor(p, off, 64);

        const float e = (base + grp < hi) ? __expf(p) : 0.0f;  // 4 rows / instr
        l_run += e;
        #pragma unroll
        for (int j = 0; j < 4; ++j) {
            acc[j].x += e * fa[j].x;
            acc[j].y += e * fa[j].y;
            acc[j].z += e * fa[j].z;
            acc[j].w += e * fa[j].w;
        }

        #pragma unroll
        for (int j = 0; j < 4; ++j) { fa[j] = fb[j]; fb[j] = ft[j]; }
    }

    // Cross-group (grp 0..3) reduce: columns identical across groups.
    #pragma unroll
    for (int off = 16; off <= 32; off <<= 1) {
        l_run += __shfl_xor(l_run, off, 64);
        #pragma unroll
        for (int j = 0; j < 4; ++j) {
            acc[j].x += __shfl_xor(acc[j].x, off, 64);
            acc[j].y += __shfl_xor(acc[j].y, off, 64);
            acc[j].z += __shfl_xor(acc[j].z, off, 64);
            acc[j].w += __shfl_xor(acc[j].w, off, 64);
        }
    }

    if (lane == 0) s_l[wave] = l_run;
    if (grp == 0) {                          // lanes 0..15 hold the wave total
        #pragma unroll
        for (int j = 0; j < 4; ++j) s_acc[wave][c + 16 * j] = acc[j];
    }
    __syncthreads();

    // Output column x=tid lives at float4 index (x>>6)*16 + ((x&63)>>2),
    // component x&3 -> flat float index == x (contiguous, conflict-free).
    float L = 0.0f, val = 0.0f;
    #pragma unroll
    for (int wv = 0; wv < NWAVES; ++wv) {
        L += s_l[wv];
        val += ((const float*)s_acc[wv])[tid];
    }
    out[(size_t)b * D + tid] = val / L;
}

extern "C" void kernel_launch(void* const* d_in, const int* in_sizes, int n_in,
                              void* d_out, int out_size, void* d_ws, size_t ws_size,
                              hipStream_t stream) {
    const float* feat = (const float*)d_in[0];
    const float* Wg   = (const float*)d_in[1];
    const int*   seg  = (const int*)d_in[3];
    float*       out  = (float*)d_out;

    const int N = in_sizes[0] / D;      // 400000
    const int B = out_size   / D;       // 1024

    gap_kernel<<<dim3(B), dim3(256), 0, stream>>>(feat, Wg, (const float*)d_in[2], seg, out, N);
}